// Round 3
// baseline (2569.585 us; speedup 1.0000x reference)
//
#include <hip/hip_runtime.h>

#define B_ 128
#define T_ 512
#define I_ 64
#define R_ 512
#define O_ 64
#define NG 8          // batch groups (16 batches each); 1 block per group
#define GB 16

typedef _Float16 f16;
typedef __attribute__((ext_vector_type(8))) _Float16 half8;
typedef __attribute__((ext_vector_type(4))) float f32x4;

#define MFMA16 __builtin_amdgcn_mfma_f32_16x16x32_f16

// RNN block: 8 waves, wave w owns rows [64w, 64w+64). NO per-step s_barrier:
// per-wave monotone LDS flags form a slice-granular distributed barrier so
// waves drift and one wave's MFMAs overlap another's tanh/publish VALU.
// W A-frags per wave: 64, keyed by ROTATED position i (ks = (2w+i)&15):
//   j==3 && i<15 -> LDS (1 read per slice, spread through the loop)
//   else         -> registers (49 frags)
#define NLW 15
#define WLDS_BYTES (8 * NLW * 1024)            // 122880
#define HOFF WLDS_BYTES
#define HBYTES 16384
#define FLGOFF (HOFF + 2 * HBYTES)             // 155648
#define SMEM_TOTAL (FLGOFF + 64)               // 155712 <= 163840

__device__ __forceinline__ float tanh_fast(float x) {
    float e = __expf(2.0f * x);
    return 1.0f - 2.0f * __builtin_amdgcn_rcpf(e + 1.0f);
}

__device__ __forceinline__ half8 cvt_h8(const float4 a, const float4 b) {
    half8 r;
    r[0] = (f16)a.x; r[1] = (f16)a.y; r[2] = (f16)a.z; r[3] = (f16)a.w;
    r[4] = (f16)b.x; r[5] = (f16)b.y; r[6] = (f16)b.z; r[7] = (f16)b.w;
    return r;
}

__device__ __forceinline__ unsigned pack2(float a, float b) {
    union { f16 h[2]; unsigned u; } r;
    r.h[0] = (f16)a; r.h[1] = (f16)b; return r.u;
}

// ------------- pre-kernel: u[t][g][b][r] (f16) = U_h . x + b_h -------------
__global__ void __launch_bounds__(256) pre_kernel(
    const float* __restrict__ x_pred, const float* __restrict__ b_h,
    const float* __restrict__ U_h, f16* __restrict__ ubuf)
{
    const int tid = threadIdx.x;
    const int w = tid >> 6, l = tid & 63, lg = l >> 4, ln = l & 15;
    const int g = blockIdx.x & 7, tc = blockIdx.x >> 3;   // 4 timesteps per block
    const int b0 = g * GB;

    half8 uf[8][2];
    float4 bh4[8];
    #pragma unroll
    for (int j = 0; j < 8; ++j) {
        const int rt = 128 * w + 16 * j;
        bh4[j] = *(const float4*)(b_h + rt + 4 * lg);
        #pragma unroll
        for (int ks = 0; ks < 2; ++ks) {
            const float* p = U_h + (size_t)(rt + ln) * I_ + 32 * ks + 8 * lg;
            uf[j][ks] = cvt_h8(*(const float4*)p, *(const float4*)(p + 4));
        }
    }
    for (int tt = 0; tt < 4; ++tt) {
        const int t = tc * 4 + tt;
        half8 xf[2];
        #pragma unroll
        for (int ks = 0; ks < 2; ++ks) {
            const float* p = x_pred + ((size_t)(b0 + ln) * T_ + t) * I_ + 32 * ks + 8 * lg;
            xf[ks] = cvt_h8(*(const float4*)p, *(const float4*)(p + 4));
        }
        char* ut = (char*)ubuf + (size_t)(t * NG + g) * 16384;
        #pragma unroll
        for (int j = 0; j < 8; ++j) {
            f32x4 acc = {0.f, 0.f, 0.f, 0.f};
            acc = MFMA16(uf[j][0], xf[0], acc, 0, 0, 0);
            acc = MFMA16(uf[j][1], xf[1], acc, 0, 0, 0);
            const int rt = 128 * w + 16 * j;
            uint2 pk;
            pk.x = pack2(acc[0] + bh4[j].x, acc[1] + bh4[j].y);
            pk.y = pack2(acc[2] + bh4[j].z, acc[3] + bh4[j].w);
            *(uint2*)(ut + ln * 1024 + 2 * (rt + 4 * lg)) = pk;   // [b][r]
        }
    }
}

// ---- RNN kernel: 1 block per group, 8 waves, flag-synced (no s_barrier) ----
__global__ void __launch_bounds__(512, 2) rnn_kernel(
    const float* __restrict__ h0, const float* __restrict__ W_h,
    f16* __restrict__ uh, float* __restrict__ out)
{
    extern __shared__ char smem[];
    const int tid = threadIdx.x;
    const int w = tid >> 6, l = tid & 63, lg = l >> 4, ln = l & 15;
    const int g = blockIdx.x;
    const int b0 = g * GB;
    const int rw = w * 64;                     // wave's first output row

    if (tid < 8) *(int*)(smem + FLGOFF + tid * 4) = 0;   // flag[w]=0: h[0] staged

    // ---- stage W rows [rw, rw+64), keyed by rotated slice index i ----
    half8 wfr[49];
    #pragma unroll
    for (int i = 0; i < 16; ++i) {
        const int ks = (2 * w + i) & 15;
        #pragma unroll
        for (int j = 0; j < 4; ++j) {
            const float* p = W_h + (size_t)(rw + 16 * j + ln) * R_ + 32 * ks + 8 * lg;
            half8 f = cvt_h8(*(const float4*)p, *(const float4*)(p + 4));
            if (j == 3) {
                if (i < 15) *(half8*)(smem + ((w * NLW + i) << 10) + (l << 4)) = f;
                else wfr[48] = f;
            } else wfr[i * 3 + j] = f;
        }
    }
    // ---- stage h0 into buffer 0 (f16, XOR-swizzled [b][r]) ----
    {
        const int b = tid >> 5, r0 = (tid & 31) * 16;
        const int sb = (b & 7) << 4;
        const float* hp = h0 + (size_t)(b0 + b) * R_ + r0;
        #pragma unroll
        for (int q = 0; q < 4; ++q) {
            float4 v = *(const float4*)(hp + 4 * q);
            uint2 pk;
            pk.x = pack2(v.x, v.y); pk.y = pack2(v.z, v.w);
            *(uint2*)(smem + HOFF + b * 1024 + ((2 * (r0 + 4 * q)) ^ sb)) = pk;
        }
    }
    // ---- prefetch u[0] ----
    uint2 uu[4];
    #pragma unroll
    for (int j = 0; j < 4; ++j)
        uu[j] = *(const uint2*)((char*)uh + (size_t)g * 16384 + ln * 1024 + 2 * (rw + 16 * j + 4 * lg));
    __syncthreads();   // one-time: W/h0/flags staged

    const int asb = (ln & 7) << 4;
    volatile const int* vf = (volatile const int*)(smem + FLGOFF);

    #pragma unroll 1
    for (int t = 0; t < T_; ++t) {
        const char* hbp = smem + HOFF + (t & 1) * HBYTES + ln * 1024;
        char* hn = smem + HOFF + ((t & 1) ^ 1) * HBYTES;
        char* slot = (char*)uh + (size_t)(t * NG + g) * 16384;
        const bool lastt = (t == T_ - 1);
        unsigned hoff_dyn = 0;   // laundered through flag checks: orders B-reads after flags

        // rolling flag prefetch for producers (w+1..w+7)&7
        int fA = vf[(w + 1) & 7], fB = vf[(w + 2) & 7], fC = vf[(w + 3) & 7], fD = vf[(w + 4) & 7];

        // acc <- u[t]
        f32x4 acc[4];
        #pragma unroll
        for (int j = 0; j < 4; ++j) {
            union { uint2 u; f16 h[4]; } c; c.u = uu[j];
            acc[j] = (f32x4){(float)c.h[0], (float)c.h[1], (float)c.h[2], (float)c.h[3]};
        }
        // prefetch u[t+1]
        if (!lastt) {
            const char* un = (const char*)uh + (size_t)((t + 1) * NG + g) * 16384;
            #pragma unroll
            for (int j = 0; j < 4; ++j)
                uu[j] = *(const uint2*)(un + ln * 1024 + 2 * (rw + 16 * j + 4 * lg));
        }

        // CHECK(c): producer (w+c)&7 must have published input t. Fast path =
        // register compare on the prefetched flag; slow path = LDS spin.
        // asm ties the flag value into the B-read base: no speculative hoisting.
        #define CHECK(c_, fvar) do {                                           \
            int fv_ = fvar;                                                    \
            if (fv_ < t) {                                                     \
                volatile const int* pp_ = vf + ((w + (c_)) & 7);               \
                do { fv_ = *pp_; } while (fv_ < t);                            \
            }                                                                  \
            asm volatile("" : "+v"(hoff_dyn) : "v"(fv_));                      \
        } while (0)

        // SLICE(i): ks = (2w+i)&15; B-frag h from LDS, A-frags reg + 1 LDS
        #define SLICE(i_) do {                                                 \
            const int ks_ = (2 * w + (i_)) & 15;                               \
            const half8 hb_ = *(const half8*)(hbp + hoff_dyn +                 \
                ((unsigned)(64 * ks_ + 16 * lg) ^ (unsigned)asb));             \
            half8 a3_;                                                         \
            if ((i_) < 15) a3_ = *(const half8*)(smem + ((w * NLW + (i_)) << 10) + (l << 4)); \
            else a3_ = wfr[48];                                                \
            acc[0] = MFMA16(wfr[(i_) * 3 + 0], hb_, acc[0], 0, 0, 0);          \
            acc[1] = MFMA16(wfr[(i_) * 3 + 1], hb_, acc[1], 0, 0, 0);          \
            acc[2] = MFMA16(wfr[(i_) * 3 + 2], hb_, acc[2], 0, 0, 0);          \
            acc[3] = MFMA16(a3_, hb_, acc[3], 0, 0, 0);                        \
        } while (0)

        SLICE(0); SLICE(1);                      // own slices: no check needed
        CHECK(1, fA); fA = vf[(w + 5) & 7];      // reissue for check 5
        SLICE(2); SLICE(3);
        CHECK(2, fB); fB = vf[(w + 6) & 7];
        SLICE(4); SLICE(5);
        CHECK(3, fC); fC = vf[(w + 7) & 7];
        SLICE(6); SLICE(7);
        CHECK(4, fD);
        SLICE(8); SLICE(9);
        CHECK(5, fA);
        SLICE(10); SLICE(11);
        CHECK(6, fB);
        SLICE(12); SLICE(13);
        CHECK(7, fC);
        SLICE(14); SLICE(15);
        #undef SLICE
        #undef CHECK

        // ---- finalize: tanh, publish h (global slot + LDS next buffer) ----
        #pragma unroll
        for (int j = 0; j < 4; ++j) {
            const int rb = 2 * (rw + 16 * j + 4 * lg);
            float v0 = tanh_fast(acc[j][0]), v1 = tanh_fast(acc[j][1]);
            float v2 = tanh_fast(acc[j][2]), v3 = tanh_fast(acc[j][3]);
            uint2 pk;
            pk.x = pack2(v0, v1); pk.y = pack2(v2, v3);
            *(uint2*)(slot + ln * 1024 + rb) = pk;               // h history [b][r]
            if (!lastt) {
                *(uint2*)(hn + ln * 1024 + (rb ^ asb)) = pk;     // LDS next buffer
            } else {
                float* xd = out + (size_t)B_ * T_ * O_ + (size_t)(b0 + ln) * R_ + (rw + 16 * j + 4 * lg);
                float4 xv = make_float4(v0, v1, v2, v3);
                *(float4*)xd = xv;
                *(float4*)(xd + (size_t)B_ * R_) = xv;
            }
        }
        // Publish: drain LDS writes, then flag[w] = t+1 (monotone). Consumers
        // seeing t+1 know (a) input t+1 rows present, (b) we finished reading
        // input t-1 (same parity they will overwrite at step t+1 finalize).
        if (!lastt) {
            asm volatile("s_waitcnt lgkmcnt(0)" ::: "memory");
            if (l == 0) *(volatile int*)(smem + FLGOFF + w * 4) = t + 1;
        }
    }
}

// ---------------- post-kernel: y[b][t][o] = W_out . h + b_out ----------------
__global__ void __launch_bounds__(256) y_kernel(
    const f16* __restrict__ hbuf, const float* __restrict__ W_out,
    const float* __restrict__ b_out, float* __restrict__ out)
{
    const int tid = threadIdx.x;
    const int w = tid >> 6, l = tid & 63, lg = l >> 4, ln = l & 15;
    const int g = blockIdx.x & 7, tc = blockIdx.x >> 3;
    const int b0 = g * GB;

    half8 wf[16];
    #pragma unroll
    for (int ks = 0; ks < 16; ++ks) {
        const float* p = W_out + (size_t)(16 * w + ln) * R_ + 32 * ks + 8 * lg;
        wf[ks] = cvt_h8(*(const float4*)p, *(const float4*)(p + 4));
    }
    const float bo = b_out[16 * w + ln];

    for (int tt = 0; tt < 4; ++tt) {
        const int t = tc * 4 + tt;
        const char* hb = (const char*)hbuf + (size_t)(t * NG + g) * 16384;   // [b][r]
        f32x4 acc = {0.f, 0.f, 0.f, 0.f};
        #pragma unroll
        for (int ks = 0; ks < 16; ++ks) {
            half8 a = *(const half8*)(hb + ln * 1024 + 64 * ks + 16 * lg);
            acc = MFMA16(a, wf[ks], acc, 0, 0, 0);
        }
        #pragma unroll
        for (int q = 0; q < 4; ++q) {
            const int b = 4 * lg + q;
            out[((size_t)(b0 + b) * T_ + t) * O_ + 16 * w + ln] = acc[q] + bo;
        }
    }
}

extern "C" void kernel_launch(void* const* d_in, const int* in_sizes, int n_in,
                              void* d_out, int out_size, void* d_ws, size_t ws_size,
                              hipStream_t stream) {
    const float* x_pred = (const float*)d_in[0];
    const float* h0     = (const float*)d_in[1];
    const float* W_h    = (const float*)d_in[2];
    const float* b_h    = (const float*)d_in[3];
    const float* U_h    = (const float*)d_in[4];
    const float* W_out  = (const float*)d_in[5];
    const float* b_out  = (const float*)d_in[6];
    float* out = (float*)d_out;

    f16* ubuf = (f16*)d_ws;   // u[t][g][b][r] f16, overwritten in-place by h[t+1]

    hipFuncSetAttribute(reinterpret_cast<const void*>(rnn_kernel),
                        hipFuncAttributeMaxDynamicSharedMemorySize, SMEM_TOTAL);

    pre_kernel<<<dim3(NG * 128), dim3(256), 0, stream>>>(x_pred, b_h, U_h, ubuf);
    rnn_kernel<<<dim3(NG), dim3(512), SMEM_TOTAL, stream>>>(h0, W_h, ubuf, out);
    y_kernel<<<dim3(NG * 128), dim3(256), 0, stream>>>(ubuf, W_out, b_out, out);
}